// Round 1
// baseline (90.929 us; speedup 1.0000x reference)
//
#include <hip/hip_runtime.h>
#include <math.h>

// CapsuleLayer collapses: b_ij starts at 0 and u_hat has no j-dependence,
// so softmax over j is uniform (1/N) at every routing iteration and
// v_j[b,j,:] == squash(mean_n u_hat[b,n,:]) for all j. Proof sketch:
//   iter0: softmax(0)=1/N -> s_j const in j -> v const in j
//   agreement = <u_hat[b,i,:], v[b,:]> const in j -> b_ij rows const in j
//   -> softmax uniform again -> fixed point. Holds bit-exactly in fp too
//   (every j executes the identical computation in the reference).
// So: out[b,j,d] = squash_d( (1/N) * sum_n sum_i x[b,n,i] * W[n,i,d] ).

#define BATCH 64
#define NCAPS 1152
#define IN_DIM 8
#define OUT_DIM 16
#define SPLIT 4                    // j-chunks per batch -> 256 blocks total
#define JCHUNK (NCAPS / SPLIT)     // 288 j's per block

__global__ __launch_bounds__(256) void capsule_kernel(
    const float* __restrict__ x,   // [B, N, IN]
    const float* __restrict__ W,   // [1, N, IN, OUT]
    float* __restrict__ out)       // [B, N, OUT]
{
    const int b   = blockIdx.x / SPLIT;
    const int c   = blockIdx.x % SPLIT;
    const int tid = threadIdx.x;
    const int d   = tid & 15;      // output dim handled by this thread
    const int n0  = tid >> 4;      // 0..15, n-stripe

    // ---- per-thread partial of sum_n u_hat[b,n,d] ----
    const float* xb = x + (size_t)b * (NCAPS * IN_DIM);
    float acc = 0.f;
    for (int n = n0; n < NCAPS; n += 16) {
        const float* xr = xb + n * IN_DIM;
        const float* wr = W + n * (IN_DIM * OUT_DIM) + d;
#pragma unroll
        for (int i = 0; i < IN_DIM; ++i)
            acc += xr[i] * wr[i * OUT_DIM];
    }

    // ---- block reduction over the 16 n-stripes (keeps d) ----
    __shared__ float s[256];
    s[tid] = acc;
    __syncthreads();
#pragma unroll
    for (int off = 128; off >= 16; off >>= 1) {
        if (tid < off) s[tid] += s[tid + off];
        __syncthreads();
    }

    __shared__ float vsh[OUT_DIM];
    if (tid < OUT_DIM) vsh[tid] = s[tid] * (1.0f / NCAPS);  // ubar[d]
    __syncthreads();

    // ---- squash (every thread redundantly, LDS broadcast reads) ----
    float sq = 0.f;
#pragma unroll
    for (int dd = 0; dd < OUT_DIM; ++dd) sq += vsh[dd] * vsh[dd];
    const float scale = sq / (1.0f + sq) / sqrtf(sq + 1e-8f);

    float4 v4[4];
#pragma unroll
    for (int g = 0; g < 4; ++g)
        v4[g] = make_float4(scale * vsh[4 * g + 0], scale * vsh[4 * g + 1],
                            scale * vsh[4 * g + 2], scale * vsh[4 * g + 3]);

    // ---- broadcast write: out[b, c*JCHUNK .. (c+1)*JCHUNK, :] ----
    float4* out4 = (float4*)out
                 + (size_t)b * (NCAPS * OUT_DIM / 4)
                 + (size_t)c * (JCHUNK * OUT_DIM / 4);
    const int total4 = JCHUNK * OUT_DIM / 4;   // 1152 float4 per block
    for (int idx = tid; idx < total4; idx += 256)
        out4[idx] = v4[idx & 3];
}

extern "C" void kernel_launch(void* const* d_in, const int* in_sizes, int n_in,
                              void* d_out, int out_size, void* d_ws, size_t ws_size,
                              hipStream_t stream) {
    const float* x = (const float*)d_in[0];
    const float* W = (const float*)d_in[1];
    float* out     = (float*)d_out;
    capsule_kernel<<<BATCH * SPLIT, 256, 0, stream>>>(x, W, out);
}

// Round 2
// 62.176 us; speedup vs baseline: 1.4624x; 1.4624x over previous
//
#include <hip/hip_runtime.h>
#include <math.h>

// CapsuleLayer routing collapses (verified R1, absmax 1.2e-4):
//   out[b,j,d] = squash_d( (1/N) * sum_{n,i} x[b,n,i] * W[n,i,d] )  for all j.
// R1 was latency-bound (49us, all pipes <10%): 256 blocks each redundantly
// ran the full 576-FMA scalar reduction. Split into:
//   K1: 64 batches x 4 n-quarters, coalesced float4 W loads -> partial sums in ws
//   K2: squash + pure coalesced broadcast write (1 float4/thread, one pass)

#define BATCH 64
#define NCAPS 1152
#define IN_DIM 8
#define OUT_DIM 16
// per batch: NCAPS*IN_DIM = 9216 x-floats; W = 9216*16 floats (576 KB total)

// ---- K1: partial reduction. grid = 64*4, block = 256 ----
// block (b, q): n-range [q*288, (q+1)*288) -> 2304 (n,i) pairs.
// thread t: dg = t&3 (4 output dims d = dg*4..dg*4+3), sidx = t>>2 (64 stripes).
// pair p = k*64 + sidx  =>  W float4 index = q*9216 + 4p + dg: lanes (dg fast,
// sidx next) read 1 KB contiguous per k-iteration. x[q*2304 + p] broadcasts
// across the 4 dg-lanes.
__global__ __launch_bounds__(256) void caps_reduce(
    const float* __restrict__ x, const float* __restrict__ W,
    float* __restrict__ ws)   // ws: [B][4][16] floats = 16 KB
{
    const int b = blockIdx.x >> 2;
    const int q = blockIdx.x & 3;
    const int t = threadIdx.x;
    const int dg = t & 3;
    const int sidx = t >> 2;

    const float*  xq = x + (size_t)b * (NCAPS * IN_DIM) + q * 2304;
    const float4* W4 = (const float4*)W + q * 9216 + dg;

    float4 acc = make_float4(0.f, 0.f, 0.f, 0.f);
#pragma unroll 4
    for (int k = 0; k < 36; ++k) {
        const int p = k * 64 + sidx;
        const float  xs = xq[p];
        const float4 w  = W4[4 * p];
        acc.x += xs * w.x; acc.y += xs * w.y;
        acc.z += xs * w.z; acc.w += xs * w.w;
    }

    __shared__ float4 red[256];
    red[t] = acc;
    __syncthreads();
#pragma unroll
    for (int off = 32; off >= 1; off >>= 1) {
        if (sidx < off) {
            float4 o = red[(sidx + off) * 4 + dg];
            float4 m = red[t];
            m.x += o.x; m.y += o.y; m.z += o.z; m.w += o.w;
            red[t] = m;
        }
        __syncthreads();
    }
    if (t < 4)   // t == dg, sidx == 0
        ((float4*)ws)[b * 16 + q * 4 + t] = red[t];
}

// ---- K2: squash + broadcast write. grid = 64*18, block = 256 ----
// out has 64*1152*16/4 = 294912 float4 = 1152 blocks * 256 threads, exactly
// one perfectly-coalesced float4 store per thread.
__global__ __launch_bounds__(256) void caps_write(
    const float* __restrict__ ws, float* __restrict__ out)
{
    const int blk = blockIdx.x;
    const int b   = blk / 18;          // 18 blocks per batch (18*256 = 4608 f4)
    const int t   = threadIdx.x;

    __shared__ float ubar[OUT_DIM];
    if (t < OUT_DIM) {
        const float* p = ws + b * 64 + t;
        ubar[t] = (p[0] + p[16] + p[32] + p[48]) * (1.0f / NCAPS);
    }
    __syncthreads();

    float sq = 0.f;
#pragma unroll
    for (int d = 0; d < OUT_DIM; ++d) sq += ubar[d] * ubar[d];
    const float scale = sq / (1.0f + sq) / sqrtf(sq + 1e-8f);

    const int dg = t & 3;              // float4 index within the 16-dim vector
    const float4 v = make_float4(scale * ubar[dg * 4 + 0],
                                 scale * ubar[dg * 4 + 1],
                                 scale * ubar[dg * 4 + 2],
                                 scale * ubar[dg * 4 + 3]);
    ((float4*)out)[(size_t)blk * 256 + t] = v;
}

extern "C" void kernel_launch(void* const* d_in, const int* in_sizes, int n_in,
                              void* d_out, int out_size, void* d_ws, size_t ws_size,
                              hipStream_t stream) {
    const float* x = (const float*)d_in[0];
    const float* W = (const float*)d_in[1];
    float* out     = (float*)d_out;
    float* ws      = (float*)d_ws;     // 16 KB used

    caps_reduce<<<BATCH * 4, 256, 0, stream>>>(x, W, ws);
    caps_write <<<BATCH * 18, 256, 0, stream>>>(ws, out);
}

// Round 3
// 60.617 us; speedup vs baseline: 1.5001x; 1.0257x over previous
//
#include <hip/hip_runtime.h>
#include <math.h>

// CapsuleLayer routing collapses (verified R1/R2, absmax 0.0):
//   out[b,j,d] = squash_d( (1/N) * sum_{n,i} x[b,n,i] * W[n,i,d] )  for all j.
// R2: K1 was still latency-bound (~15us est): 256 blocks = 1/CU, 36-deep FMA
// chain, 6-barrier LDS tree. R3: 1024 blocks (4/CU), 9 loop iters, shfl_xor
// wave reduction (1 barrier). K2 unchanged in spirit: 1 coalesced f4/thread.

#define BATCH 64
#define NCAPS 1152   // per batch: 9216 (n,i) pairs; W = 9216 float4 groups

// ---- K1: partial reduction. grid = 64 b x 16 slices, block = 256 ----
// slice s covers pairs [s*576, (s+1)*576). thread t: dg = t&3 (4 out dims),
// stripe = t>>2 (64 stripes). Per k-iter a wave reads 64 consecutive float4
// of W (1 KB contiguous); x scalar broadcasts across the 4 dg-lanes.
__global__ __launch_bounds__(256) void caps_reduce(
    const float* __restrict__ x, const float* __restrict__ W,
    float* __restrict__ ws)   // ws: [B][16][16] floats = 64 KB
{
    const int b = blockIdx.x >> 4;
    const int s = blockIdx.x & 15;
    const int t = threadIdx.x;
    const int dg = t & 3;
    const int stripe = t >> 2;

    const float*  xb = x + (size_t)b * 9216 + s * 576;
    const float4* W4 = (const float4*)W + (size_t)s * 2304 + dg;

    float4 acc = make_float4(0.f, 0.f, 0.f, 0.f);
#pragma unroll
    for (int k = 0; k < 9; ++k) {
        const int p = k * 64 + stripe;
        const float  xs = xb[p];
        const float4 w  = W4[4 * p];
        acc.x += xs * w.x; acc.y += xs * w.y;
        acc.z += xs * w.z; acc.w += xs * w.w;
    }

    // reduce over the 16 stripes within each wave (lane bits 2..5), in-register
#pragma unroll
    for (int m = 4; m <= 32; m <<= 1) {
        acc.x += __shfl_xor(acc.x, m, 64);
        acc.y += __shfl_xor(acc.y, m, 64);
        acc.z += __shfl_xor(acc.z, m, 64);
        acc.w += __shfl_xor(acc.w, m, 64);
    }

    __shared__ float4 wred[16];          // [wave][dg]
    const int wave = t >> 6;
    const int lane = t & 63;
    if (lane < 4) wred[wave * 4 + dg] = acc;   // lane == dg for lanes 0..3
    __syncthreads();

    if (t < 4) {                         // t == dg
        const float4 a = wred[t],     b4 = wred[4 + t];
        const float4 c = wred[8 + t], d4 = wred[12 + t];
        float4 r;
        r.x = (a.x + b4.x) + (c.x + d4.x);
        r.y = (a.y + b4.y) + (c.y + d4.y);
        r.z = (a.z + b4.z) + (c.z + d4.z);
        r.w = (a.w + b4.w) + (c.w + d4.w);
        ((float4*)ws)[b * 64 + s * 4 + t] = r;
    }
}

// ---- K2: combine partials + squash + broadcast write ----
// grid = 64*18 = 1152, block = 256: exactly one coalesced float4 store/thread.
__global__ __launch_bounds__(256) void caps_write(
    const float* __restrict__ ws, float* __restrict__ out)
{
    const int blk = blockIdx.x;
    const int b   = blk / 18;
    const int t   = threadIdx.x;

    __shared__ float4 sh[64];
    __shared__ float  ubar[16];
    if (t < 64) sh[t] = ((const float4*)ws)[b * 64 + t];
    __syncthreads();

    if (t < 4) {                         // t == dg
        float4 r = make_float4(0.f, 0.f, 0.f, 0.f);
#pragma unroll
        for (int s = 0; s < 16; ++s) {
            const float4 v = sh[s * 4 + t];
            r.x += v.x; r.y += v.y; r.z += v.z; r.w += v.w;
        }
        const float inv = 1.0f / (float)NCAPS;
        ubar[t * 4 + 0] = r.x * inv; ubar[t * 4 + 1] = r.y * inv;
        ubar[t * 4 + 2] = r.z * inv; ubar[t * 4 + 3] = r.w * inv;
    }
    __syncthreads();

    float sq = 0.f;
#pragma unroll
    for (int d = 0; d < 16; ++d) sq += ubar[d] * ubar[d];
    const float scale = sq / (1.0f + sq) / sqrtf(sq + 1e-8f);

    const int dg = t & 3;
    const float4 v = make_float4(scale * ubar[dg * 4 + 0],
                                 scale * ubar[dg * 4 + 1],
                                 scale * ubar[dg * 4 + 2],
                                 scale * ubar[dg * 4 + 3]);
    ((float4*)out)[(size_t)blk * 256 + t] = v;
}

extern "C" void kernel_launch(void* const* d_in, const int* in_sizes, int n_in,
                              void* d_out, int out_size, void* d_ws, size_t ws_size,
                              hipStream_t stream) {
    const float* x = (const float*)d_in[0];
    const float* W = (const float*)d_in[1];
    float* out     = (float*)d_out;
    float* ws      = (float*)d_ws;     // 64 KB used

    caps_reduce<<<BATCH * 16, 256, 0, stream>>>(x, W, ws);
    caps_write <<<BATCH * 18, 256, 0, stream>>>(ws, out);
}